// Round 7
// baseline (2430.014 us; speedup 1.0000x reference)
//
#include <hip/hip_runtime.h>
#include <hip/hip_fp16.h>

#define DIM 256
#define NC 16
#define NG 1000
#define CHUNK 6250      // 512 * 6250 = 3.2M exactly -> 1 chunk per block
#define NBLK 512
#define FT 1024

// ---------------------------------------------------------------------------
// K1: hidden[n][c] = dot(x[n], W[:,c]) + b[c], stored f16.
// ONE WAVE PER BLOCK (64 nodes), no __syncthreads anywhere in the loop.
// W: f16 in LDS (8 KB), read as ds_read_b128 with wave-uniform address
//   (broadcast, conflict-free, 1 wave-op per 8 values) -> W delivery is
//   provably cheaper than the FMAs it feeds (64 LDS ops vs ~2048 cy VALU
//   per k-tile). No per-FMA SMEM/global W traffic (round-5/6 failure).
// x: per k-tile (32 dims) staged coalesced global -> LDS at stride 36 floats
//   (144 B: 16B-aligned, bank-group (l+d4)%8 -> dense, conflict-free).
//   Next tile's 8 dwordx4 are issued before compute -> loads always in
//   flight (1563 waves x 8KB = 12.5 MB >> Little's-law 2.4 MB).
// ---------------------------------------------------------------------------
__global__ void __launch_bounds__(64) hidden_kernel(
    const float* __restrict__ x, const __half* __restrict__ wh,
    const float* __restrict__ b, __half* __restrict__ hidden, int N) {
    __shared__ float4 xs[64 * 9];        // 9216 B, stride 9 float4 per node
    __shared__ __half whs[DIM * NC];     // 8192 B

    const int lane = threadIdx.x;
    // stage W f16: 512 uint4, 8 per lane, coalesced; single wave -> lgkm only
#pragma unroll
    for (int j = 0; j < 8; ++j)
        ((uint4*)whs)[lane + j * 64] = ((const uint4*)wh)[lane + j * 64];

    const int nodeBase = blockIdx.x * 64;
    const int rj = lane >> 3, sj = lane & 7;

    float acc[NC];
#pragma unroll
    for (int c = 0; c < NC; ++c) acc[c] = b[c];

    float4 r[8];
    // instr j: 8 lanes share node (j*8+rj), each takes float4 slot sj ->
    // 128B contiguous per 8 lanes, coalesced.
#define LOADT(t)                                                            \
    {                                                                       \
        _Pragma("unroll")                                                   \
        for (int j = 0; j < 8; ++j) {                                       \
            int nn = min(nodeBase + j * 8 + rj, N - 1);                     \
            r[j] = *(const float4*)(x + (size_t)nn * DIM + (t) * 32 +       \
                                    sj * 4);                                \
        }                                                                   \
    }

    LOADT(0)
#pragma unroll
    for (int t = 0; t < 8; ++t) {
#pragma unroll
        for (int j = 0; j < 8; ++j)
            xs[(j * 8 + rj) * 9 + sj] = r[j];     // bank-dense write
        if (t < 7) LOADT(t + 1)                   // prefetch next k-tile

#pragma unroll
        for (int d4 = 0; d4 < 8; ++d4) {
            float4 xv = xs[lane * 9 + d4];        // bank-dense read
            const float xsc[4] = {xv.x, xv.y, xv.z, xv.w};
#pragma unroll
            for (int dd = 0; dd < 4; ++dd) {
                int d = t * 32 + d4 * 4 + dd;
                const uint4* wp = (const uint4*)(whs + d * NC);
                uint4 wa = wp[0], wb = wp[1];     // 2x b128 broadcast
                const __half2* ha = (const __half2*)&wa;
                const __half2* hb = (const __half2*)&wb;
#pragma unroll
                for (int q = 0; q < 4; ++q) {
                    float2 f = __half22float2(ha[q]);
                    acc[2 * q]     = fmaf(xsc[dd], f.x, acc[2 * q]);
                    acc[2 * q + 1] = fmaf(xsc[dd], f.y, acc[2 * q + 1]);
                    float2 g = __half22float2(hb[q]);
                    acc[8 + 2 * q]     = fmaf(xsc[dd], g.x, acc[8 + 2 * q]);
                    acc[8 + 2 * q + 1] = fmaf(xsc[dd], g.y, acc[8 + 2 * q + 1]);
                }
            }
        }
    }
#undef LOADT

    int node = nodeBase + lane;
    if (node < N) {
        __half hv[NC];
#pragma unroll
        for (int c = 0; c < NC; ++c) hv[c] = __float2half(acc[c]);
        uint4* dst = (uint4*)(hidden + (size_t)node * NC);
        dst[0] = ((const uint4*)hv)[0];
        dst[1] = ((const uint4*)hv)[1];
    }
}

// ---------------------------------------------------------------------------
// K2: node -> graph id (searchsorted 'right'), + fused W f32->f16 convert.
// ---------------------------------------------------------------------------
__global__ void seg_kernel(const int* __restrict__ ed_idx,
                           int* __restrict__ node_seg,
                           const float* __restrict__ W,
                           __half* __restrict__ wh, int N, int G) {
    int n = blockIdx.x * blockDim.x + threadIdx.x;
    if (n < DIM * NC) wh[n] = __float2half(W[n]);
    if (n >= N) return;
    int lo = 0, hi = G;
    while (lo < hi) {
        int mid = (lo + hi) >> 1;
        if (ed_idx[mid] <= n) lo = mid + 1; else hi = mid;
    }
    node_seg[n] = lo;
}

// ---------------------------------------------------------------------------
// K3: fused hist + in-LDS counting sort + register pooling (unchanged from
// round 6: one 6250-edge chunk per block, node_seg direct lookup, prefetch-
// pipelined pool gathers, coalesced partial slice per block).
// ---------------------------------------------------------------------------
__global__ void __launch_bounds__(FT) gcn_pool_kernel(
    const int* __restrict__ rows, const int* __restrict__ cols,
    const float* __restrict__ vals, const __half* __restrict__ hidden,
    const int* __restrict__ node_seg, float* __restrict__ partials, int nE) {
    __shared__ unsigned hist[NG];
    __shared__ unsigned cursor[NG];
    __shared__ unsigned wsum[FT / 64];
    __shared__ unsigned short raw_g[CHUNK];
    __shared__ uint2 sorted[CHUNK];

    const int t = threadIdx.x, lane = t & 63, wid = t >> 6;
    const int beg = blockIdx.x * CHUNK;
    const int cnt = min(nE - beg, CHUNK);

    for (int i = t; i < NG; i += FT) hist[i] = 0u;
    __syncthreads();

    for (int i = t; i < cnt; i += 2 * FT) {
        int i2 = i + FT;
        bool ok2 = i2 < cnt;
        int r1 = rows[beg + i];
        int r2 = rows[beg + (ok2 ? i2 : i)];
        int g1 = node_seg[r1];
        int g2 = node_seg[r2];
        raw_g[i] = (unsigned short)g1;
        if (g1 < NG) atomicAdd(&hist[g1], 1u);
        if (ok2) {
            raw_g[i2] = (unsigned short)g2;
            if (g2 < NG) atomicAdd(&hist[g2], 1u);
        }
    }
    __syncthreads();

    unsigned v = (t < NG) ? hist[t] : 0u;
    unsigned inc = v;
#pragma unroll
    for (int d = 1; d < 64; d <<= 1) {
        unsigned u = __shfl_up(inc, d);
        if (lane >= d) inc += u;
    }
    if (lane == 63) wsum[wid] = inc;
    __syncthreads();
    if (wid == 0) {
        unsigned v2 = (lane < FT / 64) ? wsum[lane] : 0u;
        unsigned inc2 = v2;
#pragma unroll
        for (int d = 1; d < FT / 64; d <<= 1) {
            unsigned u = __shfl_up(inc2, d);
            if (lane >= d) inc2 += u;
        }
        if (lane < FT / 64) wsum[lane] = inc2 - v2;
    }
    __syncthreads();
    unsigned myBeg = wsum[wid] + inc - v;
    if (t < NG) cursor[t] = myBeg;
    __syncthreads();

    for (int i = t; i < cnt; i += FT) {
        int g = raw_g[i];
        if (g < NG) {
            unsigned pos = atomicAdd(&cursor[g], 1u);
            sorted[pos] = make_uint2((unsigned)cols[beg + i],
                                     __float_as_uint(vals[beg + i]));
        }
    }
    __syncthreads();

    float acc[NC];
#pragma unroll
    for (int c = 0; c < NC; ++c) acc[c] = 0.f;

    if (t < NG && v) {
        unsigned i = myBeg, end = myBeg + v;
        uint2 cv = sorted[i];
        uint4 h0 = *(const uint4*)(hidden + (size_t)cv.x * NC);
        uint4 h1 = *(const uint4*)(hidden + (size_t)cv.x * NC + 8);
        while (i < end) {
            unsigned nx = i + 1;
            uint2 cvn = cv;
            uint4 h0n = h0, h1n = h1;
            if (nx < end) {
                cvn = sorted[nx];
                h0n = *(const uint4*)(hidden + (size_t)cvn.x * NC);
                h1n = *(const uint4*)(hidden + (size_t)cvn.x * NC + 8);
            }
            float vv = __uint_as_float(cv.y);
            const __half2* q0 = (const __half2*)&h0;
            const __half2* q1 = (const __half2*)&h1;
#pragma unroll
            for (int k = 0; k < 4; ++k) {
                float2 f0 = __half22float2(q0[k]);
                float2 f1 = __half22float2(q1[k]);
                acc[2 * k]         = fmaf(vv, f0.x, acc[2 * k]);
                acc[2 * k + 1]     = fmaf(vv, f0.y, acc[2 * k + 1]);
                acc[8 + 2 * k]     = fmaf(vv, f1.x, acc[8 + 2 * k]);
                acc[8 + 2 * k + 1] = fmaf(vv, f1.y, acc[8 + 2 * k + 1]);
            }
            cv = cvn; h0 = h0n; h1 = h1n; i = nx;
        }
    }

    if (t < NG) {
        float4* p = (float4*)(partials + ((size_t)blockIdx.x * NG + t) * NC);
        p[0] = make_float4(acc[0], acc[1], acc[2], acc[3]);
        p[1] = make_float4(acc[4], acc[5], acc[6], acc[7]);
        p[2] = make_float4(acc[8], acc[9], acc[10], acc[11]);
        p[3] = make_float4(acc[12], acc[13], acc[14], acc[15]);
    }
}

// ---------------------------------------------------------------------------
// K4: fold partials[NBLK][NG*NC] into out; blockIdx.y picks 64 slices.
// ---------------------------------------------------------------------------
__global__ void reduce_kernel(const float* __restrict__ partials,
                              float* __restrict__ out) {
    int i = blockIdx.x * blockDim.x + threadIdx.x;
    if (i >= NG * NC) return;
    const int per = NBLK / 8;  // 64
    const float* p = partials + (size_t)(blockIdx.y * per) * (NG * NC) + i;
    float s0 = 0.f, s1 = 0.f, s2 = 0.f, s3 = 0.f;
#pragma unroll 4
    for (int k = 0; k < per; k += 4) {
        s0 += p[(size_t)(k + 0) * (NG * NC)];
        s1 += p[(size_t)(k + 1) * (NG * NC)];
        s2 += p[(size_t)(k + 2) * (NG * NC)];
        s3 += p[(size_t)(k + 3) * (NG * NC)];
    }
    atomicAdd(&out[i], (s0 + s1) + (s2 + s3));
}

extern "C" void kernel_launch(void* const* d_in, const int* in_sizes, int n_in,
                              void* d_out, int out_size, void* d_ws, size_t ws_size,
                              hipStream_t stream) {
    const float* x      = (const float*)d_in[0];
    const int*   ed_idx = (const int*)  d_in[1];
    const int*   rows   = (const int*)  d_in[2];
    const int*   cols   = (const int*)  d_in[3];
    const float* vals   = (const float*)d_in[4];
    const float* W      = (const float*)d_in[5];
    const float* b      = (const float*)d_in[6];
    float* out = (float*)d_out;

    int N  = in_sizes[0] / DIM;   // 100000
    int G  = in_sizes[1];         // 1000
    int nE = in_sizes[2];         // 3200000

    size_t off = 0;
    auto alloc = [&](size_t bytes, size_t align) {
        off = (off + align - 1) / align * align;
        size_t r = off; off += bytes; return r;
    };
    __half* hidden   = (__half*)((char*)d_ws + alloc((size_t)N * NC * 2, 16));
    int*    node_seg = (int*)   ((char*)d_ws + alloc((size_t)N * 4, 16));
    float*  partials = (float*) ((char*)d_ws + alloc((size_t)NBLK * NG * NC * 4, 16));
    __half* whalf    = (__half*)((char*)d_ws + alloc((size_t)DIM * NC * 2, 16));
    (void)ws_size;

    hipMemsetAsync(d_out, 0, (size_t)out_size * sizeof(float), stream);

    seg_kernel<<<(N + 255) / 256, 256, 0, stream>>>(ed_idx, node_seg, W, whalf,
                                                    N, G);
    hidden_kernel<<<(N + 63) / 64, 64, 0, stream>>>(x, whalf, b, hidden, N);
    gcn_pool_kernel<<<NBLK, FT, 0, stream>>>(rows, cols, vals, hidden,
                                             node_seg, partials, nE);
    dim3 rg((NG * NC + 255) / 256, 8);
    reduce_kernel<<<rg, 256, 0, stream>>>(partials, out);
}

// Round 8
// 160.661 us; speedup vs baseline: 15.1251x; 15.1251x over previous
//
#include <hip/hip_runtime.h>
#include <hip/hip_fp16.h>

#define DIM 256
#define NC 16
#define NG 1000
#define CHUNK 6250      // 512 * 6250 = 3.2M exactly -> 1 chunk per block
#define NBLK 512
#define FT 1024

// ---------------------------------------------------------------------------
// K1: hidden[n][c] = dot(x[n], W[:,c]) + b[c], stored f16.
// ONE WAVE PER BLOCK (64 nodes), no __syncthreads in the loop.
// W: f32 in LDS (16 KB), wave-uniform ds_read_b128 broadcasts (conflict-free,
//   128 reads/tile vs ~1024 cy of FMA -> W delivery provably cheap).
// x: per 32-dim k-tile staged coalesced global -> LDS (stride 9 float4 =
//   bank-uniform on both write and read sides, verified round 7), with the
//   next tile's 8 dwordx4 issued before compute.
// SPILL CONTROL (round-7 lesson): k-tile loop is '#pragma unroll 1' so only
// one LOADT + one compute body is in scheduling scope (VGPR ~100, not 256).
// ---------------------------------------------------------------------------
__global__ void __launch_bounds__(64, 2) hidden_kernel(
    const float* __restrict__ x, const float* __restrict__ W,
    const float* __restrict__ b, __half* __restrict__ hidden, int N) {
    __shared__ float4 xs[64 * 9];          // 9216 B
    __shared__ float4 ws[DIM * NC / 4];    // 16384 B, W as f32 rows [d][c]

    const int lane = threadIdx.x;
    // stage W: 1024 float4, 16 per lane, coalesced (single wave, in-order LDS)
#pragma unroll
    for (int j = 0; j < 16; ++j)
        ws[lane + j * 64] = ((const float4*)W)[lane + j * 64];

    const int nodeBase = blockIdx.x * 64;
    const int rj = lane >> 3, sj = lane & 7;

    float acc[NC];
#pragma unroll
    for (int c = 0; c < NC; ++c) acc[c] = b[c];

    float4 r[8];
    // load unit j: 8 lanes share node (j*8+rj), slots sj -> 128B contiguous
    // per 8 lanes, fully coalesced per instruction.
#define LOADT(t)                                                            \
    {                                                                       \
        _Pragma("unroll")                                                   \
        for (int j = 0; j < 8; ++j) {                                       \
            int nn = min(nodeBase + j * 8 + rj, N - 1);                     \
            r[j] = *(const float4*)(x + (size_t)nn * DIM + (t) * 32 +       \
                                    sj * 4);                                \
        }                                                                   \
    }

    LOADT(0)
#pragma unroll 1
    for (int t = 0; t < 8; ++t) {
#pragma unroll
        for (int j = 0; j < 8; ++j)
            xs[(j * 8 + rj) * 9 + sj] = r[j];     // bank-uniform write
        if (t < 7) LOADT(t + 1)                   // keep next tile in flight

#pragma unroll
        for (int d4 = 0; d4 < 8; ++d4) {
            float4 xv = xs[lane * 9 + d4];        // bank-uniform read
            const float xsc[4] = {xv.x, xv.y, xv.z, xv.w};
            const int dbase = (t * 32 + d4 * 4) * (NC / 4);
#pragma unroll
            for (int dd = 0; dd < 4; ++dd) {
                const float4 w0 = ws[dbase + dd * 4 + 0];   // broadcast b128
                const float4 w1 = ws[dbase + dd * 4 + 1];
                const float4 w2 = ws[dbase + dd * 4 + 2];
                const float4 w3 = ws[dbase + dd * 4 + 3];
                const float xd = xsc[dd];
                acc[0]  = fmaf(xd, w0.x, acc[0]);
                acc[1]  = fmaf(xd, w0.y, acc[1]);
                acc[2]  = fmaf(xd, w0.z, acc[2]);
                acc[3]  = fmaf(xd, w0.w, acc[3]);
                acc[4]  = fmaf(xd, w1.x, acc[4]);
                acc[5]  = fmaf(xd, w1.y, acc[5]);
                acc[6]  = fmaf(xd, w1.z, acc[6]);
                acc[7]  = fmaf(xd, w1.w, acc[7]);
                acc[8]  = fmaf(xd, w2.x, acc[8]);
                acc[9]  = fmaf(xd, w2.y, acc[9]);
                acc[10] = fmaf(xd, w2.z, acc[10]);
                acc[11] = fmaf(xd, w2.w, acc[11]);
                acc[12] = fmaf(xd, w3.x, acc[12]);
                acc[13] = fmaf(xd, w3.y, acc[13]);
                acc[14] = fmaf(xd, w3.z, acc[14]);
                acc[15] = fmaf(xd, w3.w, acc[15]);
            }
        }
    }
#undef LOADT

    int node = nodeBase + lane;
    if (node < N) {
        __half hv[NC];
#pragma unroll
        for (int c = 0; c < NC; ++c) hv[c] = __float2half(acc[c]);
        uint4* dst = (uint4*)(hidden + (size_t)node * NC);
        dst[0] = ((const uint4*)hv)[0];
        dst[1] = ((const uint4*)hv)[1];
    }
}

// ---------------------------------------------------------------------------
// K2: node -> graph id (searchsorted 'right' over sorted ed_idx)
// ---------------------------------------------------------------------------
__global__ void seg_kernel(const int* __restrict__ ed_idx,
                           int* __restrict__ node_seg, int N, int G) {
    int n = blockIdx.x * blockDim.x + threadIdx.x;
    if (n >= N) return;
    int lo = 0, hi = G;
    while (lo < hi) {
        int mid = (lo + hi) >> 1;
        if (ed_idx[mid] <= n) lo = mid + 1; else hi = mid;
    }
    node_seg[n] = lo;
}

// ---------------------------------------------------------------------------
// K3: fused hist + in-LDS counting sort + register pooling (unchanged:
// one 6250-edge chunk per block, node_seg direct lookup, prefetch-pipelined
// pool gathers, coalesced partial slice per block).
// ---------------------------------------------------------------------------
__global__ void __launch_bounds__(FT) gcn_pool_kernel(
    const int* __restrict__ rows, const int* __restrict__ cols,
    const float* __restrict__ vals, const __half* __restrict__ hidden,
    const int* __restrict__ node_seg, float* __restrict__ partials, int nE) {
    __shared__ unsigned hist[NG];
    __shared__ unsigned cursor[NG];
    __shared__ unsigned wsum[FT / 64];
    __shared__ unsigned short raw_g[CHUNK];
    __shared__ uint2 sorted[CHUNK];

    const int t = threadIdx.x, lane = t & 63, wid = t >> 6;
    const int beg = blockIdx.x * CHUNK;
    const int cnt = min(nE - beg, CHUNK);

    for (int i = t; i < NG; i += FT) hist[i] = 0u;
    __syncthreads();

    for (int i = t; i < cnt; i += 2 * FT) {
        int i2 = i + FT;
        bool ok2 = i2 < cnt;
        int r1 = rows[beg + i];
        int r2 = rows[beg + (ok2 ? i2 : i)];
        int g1 = node_seg[r1];
        int g2 = node_seg[r2];
        raw_g[i] = (unsigned short)g1;
        if (g1 < NG) atomicAdd(&hist[g1], 1u);
        if (ok2) {
            raw_g[i2] = (unsigned short)g2;
            if (g2 < NG) atomicAdd(&hist[g2], 1u);
        }
    }
    __syncthreads();

    unsigned v = (t < NG) ? hist[t] : 0u;
    unsigned inc = v;
#pragma unroll
    for (int d = 1; d < 64; d <<= 1) {
        unsigned u = __shfl_up(inc, d);
        if (lane >= d) inc += u;
    }
    if (lane == 63) wsum[wid] = inc;
    __syncthreads();
    if (wid == 0) {
        unsigned v2 = (lane < FT / 64) ? wsum[lane] : 0u;
        unsigned inc2 = v2;
#pragma unroll
        for (int d = 1; d < FT / 64; d <<= 1) {
            unsigned u = __shfl_up(inc2, d);
            if (lane >= d) inc2 += u;
        }
        if (lane < FT / 64) wsum[lane] = inc2 - v2;
    }
    __syncthreads();
    unsigned myBeg = wsum[wid] + inc - v;
    if (t < NG) cursor[t] = myBeg;
    __syncthreads();

    for (int i = t; i < cnt; i += FT) {
        int g = raw_g[i];
        if (g < NG) {
            unsigned pos = atomicAdd(&cursor[g], 1u);
            sorted[pos] = make_uint2((unsigned)cols[beg + i],
                                     __float_as_uint(vals[beg + i]));
        }
    }
    __syncthreads();

    float acc[NC];
#pragma unroll
    for (int c = 0; c < NC; ++c) acc[c] = 0.f;

    if (t < NG && v) {
        unsigned i = myBeg, end = myBeg + v;
        uint2 cv = sorted[i];
        uint4 h0 = *(const uint4*)(hidden + (size_t)cv.x * NC);
        uint4 h1 = *(const uint4*)(hidden + (size_t)cv.x * NC + 8);
        while (i < end) {
            unsigned nx = i + 1;
            uint2 cvn = cv;
            uint4 h0n = h0, h1n = h1;
            if (nx < end) {
                cvn = sorted[nx];
                h0n = *(const uint4*)(hidden + (size_t)cvn.x * NC);
                h1n = *(const uint4*)(hidden + (size_t)cvn.x * NC + 8);
            }
            float vv = __uint_as_float(cv.y);
            const __half2* q0 = (const __half2*)&h0;
            const __half2* q1 = (const __half2*)&h1;
#pragma unroll
            for (int k = 0; k < 4; ++k) {
                float2 f0 = __half22float2(q0[k]);
                float2 f1 = __half22float2(q1[k]);
                acc[2 * k]         = fmaf(vv, f0.x, acc[2 * k]);
                acc[2 * k + 1]     = fmaf(vv, f0.y, acc[2 * k + 1]);
                acc[8 + 2 * k]     = fmaf(vv, f1.x, acc[8 + 2 * k]);
                acc[8 + 2 * k + 1] = fmaf(vv, f1.y, acc[8 + 2 * k + 1]);
            }
            cv = cvn; h0 = h0n; h1 = h1n; i = nx;
        }
    }

    if (t < NG) {
        float4* p = (float4*)(partials + ((size_t)blockIdx.x * NG + t) * NC);
        p[0] = make_float4(acc[0], acc[1], acc[2], acc[3]);
        p[1] = make_float4(acc[4], acc[5], acc[6], acc[7]);
        p[2] = make_float4(acc[8], acc[9], acc[10], acc[11]);
        p[3] = make_float4(acc[12], acc[13], acc[14], acc[15]);
    }
}

// ---------------------------------------------------------------------------
// K4: fold partials[NBLK][NG*NC] into out; blockIdx.y picks 64 slices.
// ---------------------------------------------------------------------------
__global__ void reduce_kernel(const float* __restrict__ partials,
                              float* __restrict__ out) {
    int i = blockIdx.x * blockDim.x + threadIdx.x;
    if (i >= NG * NC) return;
    const int per = NBLK / 8;  // 64
    const float* p = partials + (size_t)(blockIdx.y * per) * (NG * NC) + i;
    float s0 = 0.f, s1 = 0.f, s2 = 0.f, s3 = 0.f;
#pragma unroll 4
    for (int k = 0; k < per; k += 4) {
        s0 += p[(size_t)(k + 0) * (NG * NC)];
        s1 += p[(size_t)(k + 1) * (NG * NC)];
        s2 += p[(size_t)(k + 2) * (NG * NC)];
        s3 += p[(size_t)(k + 3) * (NG * NC)];
    }
    atomicAdd(&out[i], (s0 + s1) + (s2 + s3));
}

extern "C" void kernel_launch(void* const* d_in, const int* in_sizes, int n_in,
                              void* d_out, int out_size, void* d_ws, size_t ws_size,
                              hipStream_t stream) {
    const float* x      = (const float*)d_in[0];
    const int*   ed_idx = (const int*)  d_in[1];
    const int*   rows   = (const int*)  d_in[2];
    const int*   cols   = (const int*)  d_in[3];
    const float* vals   = (const float*)d_in[4];
    const float* W      = (const float*)d_in[5];
    const float* b      = (const float*)d_in[6];
    float* out = (float*)d_out;

    int N  = in_sizes[0] / DIM;   // 100000
    int G  = in_sizes[1];         // 1000
    int nE = in_sizes[2];         // 3200000

    size_t off = 0;
    auto alloc = [&](size_t bytes, size_t align) {
        off = (off + align - 1) / align * align;
        size_t r = off; off += bytes; return r;
    };
    __half* hidden   = (__half*)((char*)d_ws + alloc((size_t)N * NC * 2, 16));
    int*    node_seg = (int*)   ((char*)d_ws + alloc((size_t)N * 4, 16));
    float*  partials = (float*) ((char*)d_ws + alloc((size_t)NBLK * NG * NC * 4, 16));
    (void)ws_size;

    hipMemsetAsync(d_out, 0, (size_t)out_size * sizeof(float), stream);

    seg_kernel<<<(N + 255) / 256, 256, 0, stream>>>(ed_idx, node_seg, N, G);
    hidden_kernel<<<(N + 63) / 64, 64, 0, stream>>>(x, W, b, hidden, N);
    gcn_pool_kernel<<<NBLK, FT, 0, stream>>>(rows, cols, vals, hidden,
                                             node_seg, partials, nE);
    dim3 rg((NG * NC + 255) / 256, 8);
    reduce_kernel<<<rg, 256, 0, stream>>>(partials, out);
}